// Round 15
// baseline (64.972 us; speedup 1.0000x reference)
//
#include <hip/hip_runtime.h>
#include <math.h>
#include <stdint.h>

// Router: x (4,8192,1024) f32, W (64,1024) f32
// out = [ top_idx (32768,2) as float | top_gates (32768,2) | loss (1) ]
// ws  = [0,256): expert prob sums | [256,256+384K): frag-major pre-split W
//
// R15 = R14 (barrier-free k-loop) with the R14 bug fixed:
//  - R14 FAILED because the epilogue logits overlay (smem 0..8688) aliased
//    wave1's private x buffers (8192..16384); wave0 exits its k-loop early
//    (no barriers) and stomped wave1's live tile. Fix: logits live at 16384+
//    (fully disjoint). K-loop regions are wave-private -> provably race-free.
//  - W frags double-buffered in REGISTERS (wb[2][12], full unroll -> static
//    indices): iteration t issues all 16 loads for t+1 (12 W + 4 x-staging),
//    computes on resident data with zero waits, trailing s_waitcnt vmcnt(0)
//    self-syncs the wave. No __syncthreads until the ks-combine.

constexpr int DMODEL = 1024;
constexpr int NEXP   = 64;
constexpr int BM     = 32;    // tokens per block
constexpr int BK     = 64;    // K per tile
constexpr int NTOK   = 32768;
constexpr int NTILE  = DMODEL / BK;  // 16

constexpr int LSTR = 68 * 4;  // logits row stride (bytes)
constexpr int LOGB = 16384;   // logits base (after both waves' x buffers)
constexpr size_t WSPLIT_OFF   = 256;
constexpr size_t WSPLIT_BYTES = 384 * 1024;

typedef __attribute__((ext_vector_type(8))) short short8;
typedef __attribute__((ext_vector_type(4))) float f32x4;

__device__ __forceinline__ void gload16(const void* g, void* l) {
    __builtin_amdgcn_global_load_lds(
        (const __attribute__((address_space(1))) unsigned int*)g,
        (__attribute__((address_space(3))) unsigned int*)l,
        16, 0, 0);
}

// split one fp32 into 3 bf16 (truncation chunks; x = h+m+l exact to 2^-24)
__device__ __forceinline__ void split3(float x, short& h, short& m, short& l) {
    uint32_t u  = __float_as_uint(x);
    uint32_t uh = u & 0xffff0000u;
    float    r  = x - __uint_as_float(uh);
    uint32_t ur = __float_as_uint(r);
    uint32_t um = ur & 0xffff0000u;
    float    r2 = r - __uint_as_float(um);
    h = (short)(uh >> 16);
    m = (short)(um >> 16);
    l = (short)(__float_as_uint(r2) >> 16);
}

// ---- W pre-split, FRAG-MAJOR (R13-verified): frag (T,ks,nt,comp) = 1KB.
// Frag lane l holds W_comp[e = nt*16+(l&15)][k_local = (l>>4)*8..+8 within
// the ks half] — matches the A-frag k map.
__global__ void wsplit_kernel(const float* __restrict__ W, char* __restrict__ dst)
{
    const int g = blockIdx.x * 256 + threadIdx.x;   // 0..8191
    const int e = g >> 7;        // expert 0..63
    const int c = g & 127;       // 8-float chunk of the 1024-k row
    const int T   = c >> 3;
    const int q   = c & 7;
    const int ks  = q >> 2;
    const int qhi = q & 3;
    const int lane = (qhi << 4) | (e & 15);
    const int nt   = e >> 4;
    const float* src = W + (size_t)e * DMODEL + c * 8;
    const float4 a = *reinterpret_cast<const float4*>(src);
    const float4 b = *reinterpret_cast<const float4*>(src + 4);
    short8 sH, sM, sL;
    const float v[8] = {a.x, a.y, a.z, a.w, b.x, b.y, b.z, b.w};
#pragma unroll
    for (int j = 0; j < 8; ++j) {
        short h, m, l; split3(v[j], h, m, l);
        sH[j] = h; sM[j] = m; sL[j] = l;
    }
    char* base = dst + ((size_t)((T * 2 + ks) * 4 + nt) * 3) * 1024
                     + (size_t)lane * 16;
    *reinterpret_cast<short8*>(base)        = sH;
    *reinterpret_cast<short8*>(base + 1024) = sM;
    *reinterpret_cast<short8*>(base + 2048) = sL;
}

__global__ __launch_bounds__(128, 4) void router_kernel(
    const float* __restrict__ x, const char* __restrict__ wsAll,
    float* __restrict__ out, float* __restrict__ expert_sums)
{
    // LDS: [wave][buf][32 rows][128B XOR-swizzled] = 16384 (wave-private)
    // logits @16384 (32*272=8704), maxArr@25088, invArr@25216, psum@25344
    __shared__ __align__(16) char smem[25856];

    const int tid  = threadIdx.x;
    const int lane = tid & 63;
    const int w    = tid >> 6;   // wave id = ks (K32 half)
    const int ks   = w;
    const int tok0 = blockIdx.x * BM;

    f32x4 acc[2][4];
#pragma unroll
    for (int mt = 0; mt < 2; ++mt)
#pragma unroll
        for (int nt = 0; nt < 4; ++nt) acc[mt][nt] = (f32x4){0.f, 0.f, 0.f, 0.f};

    // wave-private x staging: 32 rows x 32 floats (this ks half) per tile.
    // phys: row r at r*128; phys chunk c holds logical chunk c^(r&7).
    char* const wbase = smem + w * 8192;
    auto stageX = [&](int buf, int t) {
#pragma unroll
        for (int i = 0; i < 4; ++i) {
            const int r = i * 8 + (lane >> 3);   // block-local row 0..31
            const int c = lane & 7;              // phys chunk
            const float* src = x + (size_t)(tok0 + r) * DMODEL + t * BK
                                 + ks * 32 + ((c ^ (r & 7)) << 2);
            gload16(src, wbase + buf * 4096 + i * 1024 + (size_t)lane * 16);
        }
    };
    auto loadW = [&](short8* bank, int t) {
        const char* wT = wsAll + (size_t)((t * 2 + ks) * 12) * 1024
                               + (size_t)lane * 16;
#pragma unroll
        for (int f = 0; f < 12; ++f)
            bank[f] = *reinterpret_cast<const short8*>(wT + f * 1024);
    };

    short8 wb[2][12];
    stageX(0, 0);
    loadW(wb[0], 0);
    asm volatile("s_waitcnt vmcnt(0)" ::: "memory");
    __builtin_amdgcn_sched_barrier(0);

#pragma unroll
    for (int t = 0; t < NTILE; ++t) {
        // issue ALL of t+1's loads first; compute below uses resident data
        if (t + 1 < NTILE) {
            loadW(wb[(t + 1) & 1], t + 1);
            stageX((t + 1) & 1, t + 1);
        }

        const char* xb = wbase + (t & 1) * 4096;
#pragma unroll
        for (int mt = 0; mt < 2; ++mt) {
            const int r  = mt * 16 + (lane & 15);
            const int q0 = (lane >> 4) * 2;
            const char* row = xb + r * 128;
            const float4 xa = *reinterpret_cast<const float4*>(
                row + ((q0 ^ (r & 7)) << 4));
            const float4 xc = *reinterpret_cast<const float4*>(
                row + (((q0 + 1) ^ (r & 7)) << 4));
            short8 aH, aM, aL;
            {
                const float v[8] = {xa.x, xa.y, xa.z, xa.w, xc.x, xc.y, xc.z, xc.w};
#pragma unroll
                for (int j = 0; j < 8; ++j) {
                    short h, m, l; split3(v[j], h, m, l);
                    aH[j] = h; aM[j] = m; aL[j] = l;
                }
            }
#pragma unroll
            for (int nt = 0; nt < 4; ++nt) {
                const short8 bH = wb[t & 1][nt * 3 + 0];
                const short8 bM = wb[t & 1][nt * 3 + 1];
                const short8 bL = wb[t & 1][nt * 3 + 2];
                acc[mt][nt] = __builtin_amdgcn_mfma_f32_16x16x32_bf16(aH, bH, acc[mt][nt], 0, 0, 0);
                acc[mt][nt] = __builtin_amdgcn_mfma_f32_16x16x32_bf16(aH, bM, acc[mt][nt], 0, 0, 0);
                acc[mt][nt] = __builtin_amdgcn_mfma_f32_16x16x32_bf16(aM, bH, acc[mt][nt], 0, 0, 0);
                acc[mt][nt] = __builtin_amdgcn_mfma_f32_16x16x32_bf16(aH, bL, acc[mt][nt], 0, 0, 0);
                acc[mt][nt] = __builtin_amdgcn_mfma_f32_16x16x32_bf16(aM, bM, acc[mt][nt], 0, 0, 0);
                acc[mt][nt] = __builtin_amdgcn_mfma_f32_16x16x32_bf16(aL, bH, acc[mt][nt], 0, 0, 0);
            }
        }
        // wave-local sync: t+1's x staging + W loads all landed
        asm volatile("s_waitcnt vmcnt(0)" ::: "memory");
        __builtin_amdgcn_sched_barrier(0);
    }

    // ---- combine ks halves into logits @LOGB [32 tok][LSTR] (disjoint!) ----
    // C/D: col=lane&15 (expert frag), row=(lane>>4)*4+r (verified R10)
    if (w == 0) {
#pragma unroll
        for (int mt = 0; mt < 2; ++mt)
#pragma unroll
            for (int nt = 0; nt < 4; ++nt)
#pragma unroll
                for (int r = 0; r < 4; ++r) {
                    const int tk = mt * 16 + (lane >> 4) * 4 + r;
                    const int e  = nt * 16 + (lane & 15);
                    *reinterpret_cast<float*>(smem + LOGB + tk * LSTR + e * 4) = acc[mt][nt][r];
                }
    }
    __syncthreads();
    if (w == 1) {
#pragma unroll
        for (int mt = 0; mt < 2; ++mt)
#pragma unroll
            for (int nt = 0; nt < 4; ++nt)
#pragma unroll
                for (int r = 0; r < 4; ++r) {
                    const int tk = mt * 16 + (lane >> 4) * 4 + r;
                    const int e  = nt * 16 + (lane & 15);
                    float* p = reinterpret_cast<float*>(smem + LOGB + tk * LSTR + e * 4);
                    *p += acc[mt][nt][r];
                }
    }
    __syncthreads();

    float* maxArr = reinterpret_cast<float*>(smem + 25088);
    float* invArr = reinterpret_cast<float*>(smem + 25216);
    float* psum   = reinterpret_cast<float*>(smem + 25344);

    // pass 1: per-token max, softmax denom, top-2, outputs (threads 0..31)
    if (tid < BM) {
        const char* lrow = smem + LOGB + tid * LSTR;
        float4 L[16];
#pragma unroll
        for (int i = 0; i < 16; ++i)
            L[i] = *reinterpret_cast<const float4*>(lrow + i * 16);

        float mx = -INFINITY;
#pragma unroll
        for (int i = 0; i < 16; ++i)
            mx = fmaxf(mx, fmaxf(fmaxf(L[i].x, L[i].y), fmaxf(L[i].z, L[i].w)));

        float v0 = -INFINITY, v1 = -INFINITY;
        int   i0 = NEXP, i1 = NEXP;
        float s = 0.f;
#pragma unroll
        for (int i = 0; i < 16; ++i) {
            const float vv[4] = {L[i].x, L[i].y, L[i].z, L[i].w};
#pragma unroll
            for (int c = 0; c < 4; ++c) {
                const float v = vv[c];
                const int  gi = i * 4 + c;
                s += __expf(v - mx);
                if (v > v0) { v1 = v0; i1 = i0; v0 = v; i0 = gi; }
                else if (v > v1) { v1 = v; i1 = gi; }
            }
        }
        maxArr[tid] = mx;
        invArr[tid] = 1.0f / s;

        const float q = __expf(v1 - v0);
        const float d = 1.0f + q;
        const size_t tok = (size_t)tok0 + tid;
        reinterpret_cast<float2*>(out)[tok]            = make_float2((float)i0, (float)i1);
        reinterpret_cast<float2*>(out + 2 * NTOK)[tok] = make_float2(1.0f / d, q / d);
    }
    __syncthreads();

    // pass 2: per-expert prob sums (128 thr: e = tid&63, grp = tid>>6, 16 tok)
    {
        const int e = tid & 63, grp = tid >> 6;
        float s = 0.f;
#pragma unroll
        for (int i = 0; i < 16; ++i) {
            const int tk = grp * 16 + i;
            const float lg = *reinterpret_cast<const float*>(smem + LOGB + tk * LSTR + e * 4);
            s += __expf(lg - maxArr[tk]) * invArr[tk];
        }
        psum[grp * 64 + e] = s;
    }
    __syncthreads();
    if (tid < 64) {
        atomicAdd(&expert_sums[tid], psum[tid] + psum[64 + tid]);
    }
}

// ========== fallback (ws too small): R11 kernel (512 thr, LDS W) ==========
constexpr int FBM   = 64;
constexpr int FXS   = 0;
constexpr int FXSB  = 64 * 64 * 4;
constexpr int FWS   = 32768;
constexpr int FWSB  = 3 * 64 * 64 * 2;
constexpr int FWCMP = 64 * 64 * 2;

__global__ __launch_bounds__(512, 2) void router_fallback(
    const float* __restrict__ x, const float* __restrict__ W,
    float* __restrict__ out, float* __restrict__ expert_sums)
{
    __shared__ __align__(16) char smem[81920];

    const int tid  = threadIdx.x;
    const int lane = tid & 63;
    const int w    = tid >> 6;
    const int mt   = w & 3;
    const int kh   = w >> 2;
    const int tok0 = blockIdx.x * FBM;

    f32x4 acc[4];
#pragma unroll
    for (int nt = 0; nt < 4; ++nt) acc[nt] = (f32x4){0.f, 0.f, 0.f, 0.f};

    auto stageX = [&](int buf, int tile) {
#pragma unroll
        for (int i = 0; i < 2; ++i) {
            const int r0 = w * 8 + i * 4;
            const int r  = r0 + (lane >> 4);
            const int c  = lane & 15;
            const float* src = x + (size_t)(tok0 + r) * DMODEL + tile * BK
                                 + ((c ^ (r & 15)) << 2);
            gload16(src, smem + FXS + buf * FXSB + r0 * 256 + (lane << 4));
        }
    };

    const int we  = tid >> 3;
    const int wc  = tid & 7;
    const int wph = wc ^ (we & 7);
    const float* wgp = W + (size_t)we * DMODEL + wc * 8;

    auto convW = [&](int buf, float4 a, float4 b) {
        short8 sH, sM, sL;
        float v[8] = {a.x, a.y, a.z, a.w, b.x, b.y, b.z, b.w};
#pragma unroll
        for (int j = 0; j < 8; ++j) {
            short h, m, l; split3(v[j], h, m, l);
            sH[j] = h; sM[j] = m; sL[j] = l;
        }
        char* d = smem + FWS + buf * FWSB + we * 128 + wph * 16;
        *reinterpret_cast<short8*>(d)             = sH;
        *reinterpret_cast<short8*>(d + FWCMP)     = sM;
        *reinterpret_cast<short8*>(d + 2 * FWCMP) = sL;
    };

    stageX(0, 0);
    {
        float4 a = *reinterpret_cast<const float4*>(wgp);
        float4 b = *reinterpret_cast<const float4*>(wgp + 4);
        convW(0, a, b);
    }
    __syncthreads();

    int buf = 0;
    for (int tile = 0; tile < NTILE; ++tile) {
        float4 wa, wb;
        if (tile + 1 < NTILE) {
            stageX(buf ^ 1, tile + 1);
            wa = *reinterpret_cast<const float4*>(wgp + (tile + 1) * BK);
            wb = *reinterpret_cast<const float4*>(wgp + (tile + 1) * BK + 4);
        }
        {
            const int ksl = kh;
            const int rl = mt * 16 + (lane & 15);
            const int c0 = ksl * 8 + (lane >> 4) * 2;
            const char* xrow = smem + FXS + buf * FXSB + rl * 256;
            const float4 xa = *reinterpret_cast<const float4*>(
                xrow + ((c0 ^ (rl & 15)) << 4));
            const float4 xc = *reinterpret_cast<const float4*>(
                xrow + (((c0 + 1) ^ (rl & 15)) << 4));
            short8 aH, aM, aL;
            {
                float v[8] = {xa.x, xa.y, xa.z, xa.w, xc.x, xc.y, xc.z, xc.w};
#pragma unroll
                for (int j = 0; j < 8; ++j) {
                    short h, m, l; split3(v[j], h, m, l);
                    aH[j] = h; aM[j] = m; aL[j] = l;
                }
            }
#pragma unroll
            for (int nt = 0; nt < 4; ++nt) {
                const int ef = nt * 16 + (lane & 15);
                const int q  = ksl * 4 + (lane >> 4);
                const char* wrow = smem + FWS + buf * FWSB + ef * 128
                                 + ((q ^ (ef & 7)) << 4);
                const short8 bH = *reinterpret_cast<const short8*>(wrow);
                const short8 bM = *reinterpret_cast<const short8*>(wrow + FWCMP);
                const short8 bL = *reinterpret_cast<const short8*>(wrow + 2 * FWCMP);
                acc[nt] = __builtin_amdgcn_mfma_f32_16x16x32_bf16(aH, bH, acc[nt], 0, 0, 0);
                acc[nt] = __builtin_amdgcn_mfma_f32_16x16x32_bf16(aH, bM, acc[nt], 0, 0, 0);
                acc[nt] = __builtin_amdgcn_mfma_f32_16x16x32_bf16(aM, bH, acc[nt], 0, 0, 0);
                acc[nt] = __builtin_amdgcn_mfma_f32_16x16x32_bf16(aH, bL, acc[nt], 0, 0, 0);
                acc[nt] = __builtin_amdgcn_mfma_f32_16x16x32_bf16(aM, bM, acc[nt], 0, 0, 0);
                acc[nt] = __builtin_amdgcn_mfma_f32_16x16x32_bf16(aL, bH, acc[nt], 0, 0, 0);
            }
        }
        if (tile + 1 < NTILE) convW(buf ^ 1, wa, wb);
        __syncthreads();
        buf ^= 1;
    }

    if (kh == 0) {
#pragma unroll
        for (int nt = 0; nt < 4; ++nt)
#pragma unroll
            for (int r = 0; r < 4; ++r) {
                const int t = mt * 16 + (lane >> 4) * 4 + r;
                const int e = nt * 16 + (lane & 15);
                *reinterpret_cast<float*>(smem + t * LSTR + e * 4) = acc[nt][r];
            }
    }
    __syncthreads();
    if (kh == 1) {
#pragma unroll
        for (int nt = 0; nt < 4; ++nt)
#pragma unroll
            for (int r = 0; r < 4; ++r) {
                const int t = mt * 16 + (lane >> 4) * 4 + r;
                const int e = nt * 16 + (lane & 15);
                float* p = reinterpret_cast<float*>(smem + t * LSTR + e * 4);
                *p += acc[nt][r];
            }
    }
    __syncthreads();

    float* maxArr = reinterpret_cast<float*>(smem + 18432);
    float* invArr = reinterpret_cast<float*>(smem + 18688);
    float* psum   = reinterpret_cast<float*>(smem + 18944);

    if (tid < FBM) {
        const char* lrow = smem + tid * LSTR;
        float4 L[16];
#pragma unroll
        for (int i = 0; i < 16; ++i)
            L[i] = *reinterpret_cast<const float4*>(lrow + i * 16);
        float mx = -INFINITY;
#pragma unroll
        for (int i = 0; i < 16; ++i)
            mx = fmaxf(mx, fmaxf(fmaxf(L[i].x, L[i].y), fmaxf(L[i].z, L[i].w)));
        float v0 = -INFINITY, v1 = -INFINITY;
        int   i0 = NEXP, i1 = NEXP;
        float s = 0.f;
#pragma unroll
        for (int i = 0; i < 16; ++i) {
            const float vv[4] = {L[i].x, L[i].y, L[i].z, L[i].w};
#pragma unroll
            for (int c = 0; c < 4; ++c) {
                const float v = vv[c];
                const int  gi = i * 4 + c;
                s += __expf(v - mx);
                if (v > v0) { v1 = v0; i1 = i0; v0 = v; i0 = gi; }
                else if (v > v1) { v1 = v; i1 = gi; }
            }
        }
        maxArr[tid] = mx;
        invArr[tid] = 1.0f / s;
        const float q = __expf(v1 - v0);
        const float d = 1.0f + q;
        const size_t tok = (size_t)tok0 + tid;
        reinterpret_cast<float2*>(out)[tok]            = make_float2((float)i0, (float)i1);
        reinterpret_cast<float2*>(out + 2 * NTOK)[tok] = make_float2(1.0f / d, q / d);
    }
    __syncthreads();
    {
        const int e = tid & 63, grp = tid >> 6;
        float s = 0.f;
#pragma unroll
        for (int i = 0; i < 8; ++i) {
            const int t = grp * 8 + i;
            const float lg = *reinterpret_cast<const float*>(smem + t * LSTR + e * 4);
            s += __expf(lg - maxArr[t]) * invArr[t];
        }
        psum[grp * 64 + e] = s;
    }
    __syncthreads();
    if (tid < 64) {
        float s = 0.f;
#pragma unroll
        for (int g = 0; g < 8; ++g) s += psum[g * 64 + tid];
        atomicAdd(&expert_sums[tid], s);
    }
}

__global__ void loss_kernel(const float* __restrict__ sums, float* __restrict__ out)
{
    const int lane = threadIdx.x;  // 64 threads
    float pv = sums[lane] * (1.0f / (float)NTOK);  // avg_probs[lane]
    float m = pv;
#pragma unroll
    for (int off = 32; off; off >>= 1) m += __shfl_xor(m, off, 64);
    m *= (1.0f / (float)NEXP);
    float d = pv - m;
    float v = d * d;
#pragma unroll
    for (int off = 32; off; off >>= 1) v += __shfl_xor(v, off, 64);
    v *= (1.0f / (float)(NEXP - 1));  // ddof=1
    if (lane == 0) {
        float stdv = sqrtf(v);
        float r = stdv / (m + 1e-6f);
        out[4 * NTOK] = r * r;
    }
}

extern "C" void kernel_launch(void* const* d_in, const int* in_sizes, int n_in,
                              void* d_out, int out_size, void* d_ws, size_t ws_size,
                              hipStream_t stream)
{
    const float* x = (const float*)d_in[0];
    const float* W = (const float*)d_in[1];
    float* out  = (float*)d_out;
    float* sums = (float*)d_ws;

    hipMemsetAsync(d_ws, 0, 256, stream);

    if (ws_size >= WSPLIT_OFF + WSPLIT_BYTES) {
        char* wsAll = (char*)d_ws + WSPLIT_OFF;
        hipLaunchKernelGGL(wsplit_kernel, dim3(32), dim3(256), 0, stream, W, wsAll);
        hipLaunchKernelGGL(router_kernel, dim3(NTOK / BM), dim3(128), 0, stream,
                           x, wsAll, out, sums);
    } else {
        hipLaunchKernelGGL(router_fallback, dim3(NTOK / FBM), dim3(512), 0, stream,
                           x, W, out, sums);
    }
    hipLaunchKernelGGL(loss_kernel, dim3(1), dim3(64), 0, stream, sums, out);
}

// Round 16
// 58.928 us; speedup vs baseline: 1.1026x; 1.1026x over previous
//
#include <hip/hip_runtime.h>
#include <math.h>
#include <stdint.h>

// Router: x (4,8192,1024) f32, W (64,1024) f32
// out = [ top_idx (32768,2) as float | top_gates (32768,2) | loss (1) ]
// ws  = [0,256): expert prob sums | [256,256+384K): frag-major pre-split W
//
// R16 = verified pieces of R12 (conflict-free 256B-row x swizzle) + R13
// (W frags in registers, verified maps/epilogue) + 3-deep x prefetch:
//   per tile: vmcnt(4) -> s_barrier -> issue {W(t+1)->regs, x(t+2)->LDS}
//             -> compute(t)
// Barrier BEFORE issues makes the 3-buffer rotation race-free (all waves
// finished reading buf((t+2)%3)=buf(t-1) at barrier(t)). One barrier/tile.
// 256-thr blocks, wave=(ks,nh); LDS 50688 -> 3 blocks/CU; (256,3) VGPR cap.

constexpr int DMODEL = 1024;
constexpr int NEXP   = 64;
constexpr int BM     = 64;    // tokens per block
constexpr int BK     = 64;    // K per tile
constexpr int NTOK   = 32768;
constexpr int NTILE  = DMODEL / BK;  // 16

constexpr int LSTR = 68 * 4;  // logits row stride (bytes)
constexpr int XBUF = 16384;   // one x buffer (64 rows x 256B)
constexpr size_t WSPLIT_OFF   = 256;
constexpr size_t WSPLIT_BYTES = 384 * 1024;

typedef __attribute__((ext_vector_type(8))) short short8;
typedef __attribute__((ext_vector_type(4))) float f32x4;

__device__ __forceinline__ void gload16(const void* g, void* l) {
    __builtin_amdgcn_global_load_lds(
        (const __attribute__((address_space(1))) unsigned int*)g,
        (__attribute__((address_space(3))) unsigned int*)l,
        16, 0, 0);
}

// split one fp32 into 3 bf16 (truncation chunks; x = h+m+l exact to 2^-24)
__device__ __forceinline__ void split3(float x, short& h, short& m, short& l) {
    uint32_t u  = __float_as_uint(x);
    uint32_t uh = u & 0xffff0000u;
    float    r  = x - __uint_as_float(uh);
    uint32_t ur = __float_as_uint(r);
    uint32_t um = ur & 0xffff0000u;
    float    r2 = r - __uint_as_float(um);
    h = (short)(uh >> 16);
    m = (short)(um >> 16);
    l = (short)(__float_as_uint(r2) >> 16);
}

// ---- W pre-split, FRAG-MAJOR (R13-verified): frag (T,ks,nt,comp) = 1KB.
// Frag lane l holds W_comp[e = nt*16+(l&15)][k chunk q = ks*4+(l>>4)].
__global__ void wsplit_kernel(const float* __restrict__ W, char* __restrict__ dst)
{
    const int g = blockIdx.x * 256 + threadIdx.x;   // 0..8191
    const int e = g >> 7;        // expert 0..63
    const int c = g & 127;       // 8-float chunk of the 1024-k row
    const int T   = c >> 3;
    const int q   = c & 7;
    const int ks  = q >> 2;
    const int qhi = q & 3;
    const int lane = (qhi << 4) | (e & 15);
    const int nt   = e >> 4;
    const float* src = W + (size_t)e * DMODEL + c * 8;
    const float4 a = *reinterpret_cast<const float4*>(src);
    const float4 b = *reinterpret_cast<const float4*>(src + 4);
    short8 sH, sM, sL;
    const float v[8] = {a.x, a.y, a.z, a.w, b.x, b.y, b.z, b.w};
#pragma unroll
    for (int j = 0; j < 8; ++j) {
        short h, m, l; split3(v[j], h, m, l);
        sH[j] = h; sM[j] = m; sL[j] = l;
    }
    char* base = dst + ((size_t)((T * 2 + ks) * 4 + nt) * 3) * 1024
                     + (size_t)lane * 16;
    *reinterpret_cast<short8*>(base)        = sH;
    *reinterpret_cast<short8*>(base + 1024) = sM;
    *reinterpret_cast<short8*>(base + 2048) = sL;
}

__global__ __launch_bounds__(256, 3) void router_kernel(
    const float* __restrict__ x, const char* __restrict__ wsAll,
    float* __restrict__ out, float* __restrict__ expert_sums)
{
    // LDS: 3 x-buffers @0 (3*16384=49152; R12 256B-row swizzle, conflict-free)
    // logits overlay @0 after k-loop (64*272=17408)
    // maxArr@49152, invArr@49408, psum[4][64]@49664 -> total 50688
    __shared__ __align__(16) char smem[50688];

    const int tid  = threadIdx.x;
    const int lane = tid & 63;
    const int w    = tid >> 6;   // 0..3
    const int ks   = w & 1;      // K32 half
    const int nh   = w >> 1;     // expert half (2 nt)
    const int tok0 = blockIdx.x * BM;

    f32x4 acc[4][2];
#pragma unroll
    for (int mt = 0; mt < 4; ++mt)
#pragma unroll
        for (int j = 0; j < 2; ++j) acc[mt][j] = (f32x4){0.f, 0.f, 0.f, 0.f};

    // x staging (R12-verified swizzle): phys chunk c of row r holds c^(r&15)
    auto stageX = [&](int buf, int t) {
#pragma unroll
        for (int i = 0; i < 4; ++i) {
            const int flat = i * 256 + tid;
            const int r = flat >> 4;
            const int c = flat & 15;
            const float* src = x + (size_t)(tok0 + r) * DMODEL + t * BK
                                 + ((c ^ (r & 15)) << 2);
            gload16(src, smem + buf * XBUF + flat * 16);
        }
    };
    // W frag loads: 6 per tile (2 nt x 3 comp) for this wave's ks (R13 map)
    auto loadW = [&](short8* bank, int t) {
        const char* wT = wsAll + (size_t)lane * 16;
#pragma unroll
        for (int j = 0; j < 2; ++j)
#pragma unroll
            for (int cp = 0; cp < 3; ++cp) {
                const int fi = ((t * 2 + ks) * 4 + (nh * 2 + j)) * 3 + cp;
                bank[j * 3 + cp] = *reinterpret_cast<const short8*>(
                    wT + (size_t)fi * 1024);
            }
    };

    short8 wb0[6], wb1[6];
    // prologue order [x0, W0, x1] so vmcnt(4) at t=0 allows x1 in flight
    stageX(0, 0);
    loadW(wb0, 0);
    stageX(1, 1);

#pragma unroll
    for (int t = 0; t < NTILE; ++t) {
        // wait: x(t) + W(t) landed; x(t+1) (4 loads) may remain in flight
        if (t == NTILE - 1) asm volatile("s_waitcnt vmcnt(0)" ::: "memory");
        else                asm volatile("s_waitcnt vmcnt(4)" ::: "memory");
        __builtin_amdgcn_sched_barrier(0);
        __builtin_amdgcn_s_barrier();   // all waves' x(t) staged; buf(t-1) free
        __builtin_amdgcn_sched_barrier(0);

        // issue next: W(t+1) -> other bank, x(t+2) -> buf[(t+2)%3]
        if (t + 1 < NTILE) loadW((t & 1) ? wb0 : wb1, t + 1);
        if (t + 2 < NTILE) stageX((t + 2) % 3, t + 2);

        const char* xb = smem + (t % 3) * XBUF;
        const short8* wbank = (t & 1) ? wb1 : wb0;
#pragma unroll
        for (int mt = 0; mt < 4; ++mt) {
            const int rl = mt * 16 + (lane & 15);
            const int c0 = ks * 8 + (lane >> 4) * 2;
            const char* xrow = xb + rl * 256;
            const float4 xa = *reinterpret_cast<const float4*>(
                xrow + ((c0 ^ (rl & 15)) << 4));
            const float4 xc = *reinterpret_cast<const float4*>(
                xrow + (((c0 + 1) ^ (rl & 15)) << 4));
            short8 aH, aM, aL;
            {
                const float v[8] = {xa.x, xa.y, xa.z, xa.w, xc.x, xc.y, xc.z, xc.w};
#pragma unroll
                for (int jj = 0; jj < 8; ++jj) {
                    short h, m, l; split3(v[jj], h, m, l);
                    aH[jj] = h; aM[jj] = m; aL[jj] = l;
                }
            }
#pragma unroll
            for (int j = 0; j < 2; ++j) {
                const short8 bH = wbank[j * 3 + 0];
                const short8 bM = wbank[j * 3 + 1];
                const short8 bL = wbank[j * 3 + 2];
                acc[mt][j] = __builtin_amdgcn_mfma_f32_16x16x32_bf16(aH, bH, acc[mt][j], 0, 0, 0);
                acc[mt][j] = __builtin_amdgcn_mfma_f32_16x16x32_bf16(aH, bM, acc[mt][j], 0, 0, 0);
                acc[mt][j] = __builtin_amdgcn_mfma_f32_16x16x32_bf16(aM, bH, acc[mt][j], 0, 0, 0);
                acc[mt][j] = __builtin_amdgcn_mfma_f32_16x16x32_bf16(aH, bL, acc[mt][j], 0, 0, 0);
                acc[mt][j] = __builtin_amdgcn_mfma_f32_16x16x32_bf16(aM, bM, acc[mt][j], 0, 0, 0);
                acc[mt][j] = __builtin_amdgcn_mfma_f32_16x16x32_bf16(aL, bH, acc[mt][j], 0, 0, 0);
            }
        }
    }
    __syncthreads();   // all waves done reading x bufs before logits overlay

    // ---- combine ks halves into LDS logits [64 tok][LSTR] (overlay @0) ----
    // C/D: col=lane&15 (expert frag), row=(lane>>4)*4+r (verified R10-R13)
    if (ks == 0) {
#pragma unroll
        for (int mt = 0; mt < 4; ++mt)
#pragma unroll
            for (int j = 0; j < 2; ++j)
#pragma unroll
                for (int r = 0; r < 4; ++r) {
                    const int tk = mt * 16 + (lane >> 4) * 4 + r;
                    const int e  = (nh * 2 + j) * 16 + (lane & 15);
                    *reinterpret_cast<float*>(smem + tk * LSTR + e * 4) = acc[mt][j][r];
                }
    }
    __syncthreads();
    if (ks == 1) {
#pragma unroll
        for (int mt = 0; mt < 4; ++mt)
#pragma unroll
            for (int j = 0; j < 2; ++j)
#pragma unroll
                for (int r = 0; r < 4; ++r) {
                    const int tk = mt * 16 + (lane >> 4) * 4 + r;
                    const int e  = (nh * 2 + j) * 16 + (lane & 15);
                    float* p = reinterpret_cast<float*>(smem + tk * LSTR + e * 4);
                    *p += acc[mt][j][r];
                }
    }
    __syncthreads();

    float* maxArr = reinterpret_cast<float*>(smem + 49152);
    float* invArr = reinterpret_cast<float*>(smem + 49408);
    float* psum   = reinterpret_cast<float*>(smem + 49664);

    // pass 1: per-token max, softmax denom, top-2, outputs (threads 0..63)
    if (tid < BM) {
        const char* lrow = smem + tid * LSTR;
        float4 L[16];
#pragma unroll
        for (int i = 0; i < 16; ++i)
            L[i] = *reinterpret_cast<const float4*>(lrow + i * 16);

        float mx = -INFINITY;
#pragma unroll
        for (int i = 0; i < 16; ++i)
            mx = fmaxf(mx, fmaxf(fmaxf(L[i].x, L[i].y), fmaxf(L[i].z, L[i].w)));

        float v0 = -INFINITY, v1 = -INFINITY;
        int   i0 = NEXP, i1 = NEXP;
        float s = 0.f;
#pragma unroll
        for (int i = 0; i < 16; ++i) {
            const float vv[4] = {L[i].x, L[i].y, L[i].z, L[i].w};
#pragma unroll
            for (int c = 0; c < 4; ++c) {
                const float v = vv[c];
                const int  gi = i * 4 + c;
                s += __expf(v - mx);
                if (v > v0) { v1 = v0; i1 = i0; v0 = v; i0 = gi; }
                else if (v > v1) { v1 = v; i1 = gi; }
            }
        }
        maxArr[tid] = mx;
        invArr[tid] = 1.0f / s;

        const float q = __expf(v1 - v0);
        const float d = 1.0f + q;
        const size_t tok = (size_t)tok0 + tid;
        reinterpret_cast<float2*>(out)[tok]            = make_float2((float)i0, (float)i1);
        reinterpret_cast<float2*>(out + 2 * NTOK)[tok] = make_float2(1.0f / d, q / d);
    }
    __syncthreads();

    // pass 2: per-expert prob sums (256 thr: e = tid&63, grp = tid>>6, 16 tok)
    {
        const int e = tid & 63, grp = tid >> 6;
        float s = 0.f;
#pragma unroll
        for (int i = 0; i < 16; ++i) {
            const int tk = grp * 16 + i;
            const float lg = *reinterpret_cast<const float*>(smem + tk * LSTR + e * 4);
            s += __expf(lg - maxArr[tk]) * invArr[tk];
        }
        psum[grp * 64 + e] = s;
    }
    __syncthreads();
    if (tid < 64) {
        const float s = (psum[tid] + psum[64 + tid]) + (psum[128 + tid] + psum[192 + tid]);
        atomicAdd(&expert_sums[tid], s);
    }
}

// ========== fallback (ws too small): R11 kernel (512 thr, LDS W) ==========
constexpr int FBM   = 64;
constexpr int FXS   = 0;
constexpr int FXSB  = 64 * 64 * 4;
constexpr int FWS   = 32768;
constexpr int FWSB  = 3 * 64 * 64 * 2;
constexpr int FWCMP = 64 * 64 * 2;

__global__ __launch_bounds__(512, 2) void router_fallback(
    const float* __restrict__ x, const float* __restrict__ W,
    float* __restrict__ out, float* __restrict__ expert_sums)
{
    __shared__ __align__(16) char smem[81920];

    const int tid  = threadIdx.x;
    const int lane = tid & 63;
    const int w    = tid >> 6;
    const int mt   = w & 3;
    const int kh   = w >> 2;
    const int tok0 = blockIdx.x * FBM;

    f32x4 acc[4];
#pragma unroll
    for (int nt = 0; nt < 4; ++nt) acc[nt] = (f32x4){0.f, 0.f, 0.f, 0.f};

    auto stageX = [&](int buf, int tile) {
#pragma unroll
        for (int i = 0; i < 2; ++i) {
            const int r0 = w * 8 + i * 4;
            const int r  = r0 + (lane >> 4);
            const int c  = lane & 15;
            const float* src = x + (size_t)(tok0 + r) * DMODEL + tile * BK
                                 + ((c ^ (r & 15)) << 2);
            gload16(src, smem + FXS + buf * FXSB + r0 * 256 + (lane << 4));
        }
    };

    const int we  = tid >> 3;
    const int wc  = tid & 7;
    const int wph = wc ^ (we & 7);
    const float* wgp = W + (size_t)we * DMODEL + wc * 8;

    auto convW = [&](int buf, float4 a, float4 b) {
        short8 sH, sM, sL;
        float v[8] = {a.x, a.y, a.z, a.w, b.x, b.y, b.z, b.w};
#pragma unroll
        for (int j = 0; j < 8; ++j) {
            short h, m, l; split3(v[j], h, m, l);
            sH[j] = h; sM[j] = m; sL[j] = l;
        }
        char* d = smem + FWS + buf * FWSB + we * 128 + wph * 16;
        *reinterpret_cast<short8*>(d)             = sH;
        *reinterpret_cast<short8*>(d + FWCMP)     = sM;
        *reinterpret_cast<short8*>(d + 2 * FWCMP) = sL;
    };

    stageX(0, 0);
    {
        float4 a = *reinterpret_cast<const float4*>(wgp);
        float4 b = *reinterpret_cast<const float4*>(wgp + 4);
        convW(0, a, b);
    }
    __syncthreads();

    int buf = 0;
    for (int tile = 0; tile < NTILE; ++tile) {
        float4 wa, wb;
        if (tile + 1 < NTILE) {
            stageX(buf ^ 1, tile + 1);
            wa = *reinterpret_cast<const float4*>(wgp + (tile + 1) * BK);
            wb = *reinterpret_cast<const float4*>(wgp + (tile + 1) * BK + 4);
        }
        {
            const int ksl = kh;
            const int rl = mt * 16 + (lane & 15);
            const int c0 = ksl * 8 + (lane >> 4) * 2;
            const char* xrow = smem + FXS + buf * FXSB + rl * 256;
            const float4 xa = *reinterpret_cast<const float4*>(
                xrow + ((c0 ^ (rl & 15)) << 4));
            const float4 xc = *reinterpret_cast<const float4*>(
                xrow + (((c0 + 1) ^ (rl & 15)) << 4));
            short8 aH, aM, aL;
            {
                float v[8] = {xa.x, xa.y, xa.z, xa.w, xc.x, xc.y, xc.z, xc.w};
#pragma unroll
                for (int j = 0; j < 8; ++j) {
                    short h, m, l; split3(v[j], h, m, l);
                    aH[j] = h; aM[j] = m; aL[j] = l;
                }
            }
#pragma unroll
            for (int nt = 0; nt < 4; ++nt) {
                const int ef = nt * 16 + (lane & 15);
                const int q  = ksl * 4 + (lane >> 4);
                const char* wrow = smem + FWS + buf * FWSB + ef * 128
                                 + ((q ^ (ef & 7)) << 4);
                const short8 bH = *reinterpret_cast<const short8*>(wrow);
                const short8 bM = *reinterpret_cast<const short8*>(wrow + FWCMP);
                const short8 bL = *reinterpret_cast<const short8*>(wrow + 2 * FWCMP);
                acc[nt] = __builtin_amdgcn_mfma_f32_16x16x32_bf16(aH, bH, acc[nt], 0, 0, 0);
                acc[nt] = __builtin_amdgcn_mfma_f32_16x16x32_bf16(aH, bM, acc[nt], 0, 0, 0);
                acc[nt] = __builtin_amdgcn_mfma_f32_16x16x32_bf16(aM, bH, acc[nt], 0, 0, 0);
                acc[nt] = __builtin_amdgcn_mfma_f32_16x16x32_bf16(aH, bL, acc[nt], 0, 0, 0);
                acc[nt] = __builtin_amdgcn_mfma_f32_16x16x32_bf16(aM, bM, acc[nt], 0, 0, 0);
                acc[nt] = __builtin_amdgcn_mfma_f32_16x16x32_bf16(aL, bH, acc[nt], 0, 0, 0);
            }
        }
        if (tile + 1 < NTILE) convW(buf ^ 1, wa, wb);
        __syncthreads();
        buf ^= 1;
    }

    if (kh == 0) {
#pragma unroll
        for (int nt = 0; nt < 4; ++nt)
#pragma unroll
            for (int r = 0; r < 4; ++r) {
                const int t = mt * 16 + (lane >> 4) * 4 + r;
                const int e = nt * 16 + (lane & 15);
                *reinterpret_cast<float*>(smem + t * LSTR + e * 4) = acc[nt][r];
            }
    }
    __syncthreads();
    if (kh == 1) {
#pragma unroll
        for (int nt = 0; nt < 4; ++nt)
#pragma unroll
            for (int r = 0; r < 4; ++r) {
                const int t = mt * 16 + (lane >> 4) * 4 + r;
                const int e = nt * 16 + (lane & 15);
                float* p = reinterpret_cast<float*>(smem + t * LSTR + e * 4);
                *p += acc[nt][r];
            }
    }
    __syncthreads();

    float* maxArr = reinterpret_cast<float*>(smem + 18432);
    float* invArr = reinterpret_cast<float*>(smem + 18688);
    float* psum   = reinterpret_cast<float*>(smem + 18944);

    if (tid < FBM) {
        const char* lrow = smem + tid * LSTR;
        float4 L[16];
#pragma unroll
        for (int i = 0; i < 16; ++i)
            L[i] = *reinterpret_cast<const float4*>(lrow + i * 16);
        float mx = -INFINITY;
#pragma unroll
        for (int i = 0; i < 16; ++i)
            mx = fmaxf(mx, fmaxf(fmaxf(L[i].x, L[i].y), fmaxf(L[i].z, L[i].w)));
        float v0 = -INFINITY, v1 = -INFINITY;
        int   i0 = NEXP, i1 = NEXP;
        float s = 0.f;
#pragma unroll
        for (int i = 0; i < 16; ++i) {
            const float vv[4] = {L[i].x, L[i].y, L[i].z, L[i].w};
#pragma unroll
            for (int c = 0; c < 4; ++c) {
                const float v = vv[c];
                const int  gi = i * 4 + c;
                s += __expf(v - mx);
                if (v > v0) { v1 = v0; i1 = i0; v0 = v; i0 = gi; }
                else if (v > v1) { v1 = v; i1 = gi; }
            }
        }
        maxArr[tid] = mx;
        invArr[tid] = 1.0f / s;
        const float q = __expf(v1 - v0);
        const float d = 1.0f + q;
        const size_t tok = (size_t)tok0 + tid;
        reinterpret_cast<float2*>(out)[tok]            = make_float2((float)i0, (float)i1);
        reinterpret_cast<float2*>(out + 2 * NTOK)[tok] = make_float2(1.0f / d, q / d);
    }
    __syncthreads();
    {
        const int e = tid & 63, grp = tid >> 6;
        float s = 0.f;
#pragma unroll
        for (int i = 0; i < 8; ++i) {
            const int t = grp * 8 + i;
            const float lg = *reinterpret_cast<const float*>(smem + t * LSTR + e * 4);
            s += __expf(lg - maxArr[t]) * invArr[t];
        }
        psum[grp * 64 + e] = s;
    }
    __syncthreads();
    if (tid < 64) {
        float s = 0.f;
#pragma unroll
        for (int g = 0; g < 8; ++g) s += psum[g * 64 + tid];
        atomicAdd(&expert_sums[tid], s);
    }
}

__global__ void loss_kernel(const float* __restrict__ sums, float* __restrict__ out)
{
    const int lane = threadIdx.x;  // 64 threads
    float pv = sums[lane] * (1.0f / (float)NTOK);  // avg_probs[lane]
    float m = pv;
#pragma unroll
    for (int off = 32; off; off >>= 1) m += __shfl_xor(m, off, 64);
    m *= (1.0f / (float)NEXP);
    float d = pv - m;
    float v = d * d;
#pragma unroll
    for (int off = 32; off; off >>= 1) v += __shfl_xor(v, off, 64);
    v *= (1.0f / (float)(NEXP - 1));  // ddof=1
    if (lane == 0) {
        float stdv = sqrtf(v);
        float r = stdv / (m + 1e-6f);
        out[4 * NTOK] = r * r;
    }
}

extern "C" void kernel_launch(void* const* d_in, const int* in_sizes, int n_in,
                              void* d_out, int out_size, void* d_ws, size_t ws_size,
                              hipStream_t stream)
{
    const float* x = (const float*)d_in[0];
    const float* W = (const float*)d_in[1];
    float* out  = (float*)d_out;
    float* sums = (float*)d_ws;

    hipMemsetAsync(d_ws, 0, 256, stream);

    if (ws_size >= WSPLIT_OFF + WSPLIT_BYTES) {
        char* wsAll = (char*)d_ws + WSPLIT_OFF;
        hipLaunchKernelGGL(wsplit_kernel, dim3(32), dim3(256), 0, stream, W, wsAll);
        hipLaunchKernelGGL(router_kernel, dim3(NTOK / BM), dim3(256), 0, stream,
                           x, wsAll, out, sums);
    } else {
        hipLaunchKernelGGL(router_fallback, dim3(NTOK / FBM), dim3(512), 0, stream,
                           x, W, out, sums);
    }
    hipLaunchKernelGGL(loss_kernel, dim3(1), dim3(64), 0, stream, sums, out);
}

// Round 17
// 53.297 us; speedup vs baseline: 1.2191x; 1.1057x over previous
//
#include <hip/hip_runtime.h>
#include <math.h>
#include <stdint.h>

// Router: x (4,8192,1024) f32, W (64,1024) f32
// out = [ top_idx (32768,2) as float | top_gates (32768,2) | loss (1) ]
// ws  = [0,256) expert prob sums | [256,260) done-counter | [512, 512+384K) W
//
// R17 = R12 router core (best measured: 51.6us) + launch-graph slimming:
//  - prep_kernel = wsplit + ws zeroing (replaces hipMemsetAsync + wsplit)
//  - loss inlined into the LAST router block via ticket counter
//    (threadfence + atomic ticket; sums read via atomicAdd(p,0) so the
//    values come from L2, per G16 coherence rules)
// Pipeline: 2 graph nodes instead of 4.

constexpr int DMODEL = 1024;
constexpr int NEXP   = 64;
constexpr int BM     = 64;    // tokens per block
constexpr int BK     = 64;    // K per tile
constexpr int NTOK   = 32768;
constexpr int NTILE  = DMODEL / BK;  // 16

// LDS map (bytes), total 81920 (80 KB), 2 blocks/CU:
//   XS @ 0     : fp32 x tile [2][64][64], chunk-swizzled        (32768)
//   WS @ 32768 : bf16 W split [2][3 comp][64 e][64 k], swizzled (49152)
// epilogue overlay @0: logits [64][68 f32], maxArr@18432, invArr@18688,
//   psum[8][64]@18944, isLast@20992
constexpr int XS   = 0;
constexpr int XSB  = 64 * 64 * 4;           // 16384 per buffer
constexpr int WS   = 32768;
constexpr int WSB  = 3 * 64 * 64 * 2;       // 24576 per buffer
constexpr int WCMP = 64 * 64 * 2;           // 8192 per component
constexpr int LSTR = 68 * 4;                // logits row stride (bytes)

constexpr size_t WSPLIT_OFF   = 512;
constexpr size_t WSPLIT_BYTES = (size_t)NTILE * WSB;   // 393216

typedef __attribute__((ext_vector_type(8))) short short8;
typedef __attribute__((ext_vector_type(4))) float f32x4;

__device__ __forceinline__ void gload16(const void* g, void* l) {
    __builtin_amdgcn_global_load_lds(
        (const __attribute__((address_space(1))) unsigned int*)g,
        (__attribute__((address_space(3))) unsigned int*)l,
        16, 0, 0);
}

// split one fp32 into 3 bf16 (truncation chunks; x = h+m+l exact to 2^-24)
__device__ __forceinline__ void split3(float x, short& h, short& m, short& l) {
    uint32_t u  = __float_as_uint(x);
    uint32_t uh = u & 0xffff0000u;
    float    r  = x - __uint_as_float(uh);
    uint32_t ur = __float_as_uint(r);
    uint32_t um = ur & 0xffff0000u;
    float    r2 = r - __uint_as_float(um);
    h = (short)(uh >> 16);
    m = (short)(um >> 16);
    l = (short)(__float_as_uint(r2) >> 16);
}

// ---- prep: zero sums+counter AND pre-split W (frag layout as R12) ----
__global__ void prep_kernel(const float* __restrict__ W, char* __restrict__ dst,
                            int* __restrict__ zero_base)
{
    if (blockIdx.x == 0 && threadIdx.x < 128)
        zero_base[threadIdx.x] = 0;   // ws[0,512) = sums + counter

    const int g = blockIdx.x * 256 + threadIdx.x;   // 0..8191
    const int e = g >> 7;        // expert 0..63
    const int c = g & 127;       // 8-float chunk within the 1024-k row
    const int tile = c >> 3;
    const int q    = c & 7;
    const float* src = W + (size_t)e * DMODEL + c * 8;
    const float4 a = *reinterpret_cast<const float4*>(src);
    const float4 b = *reinterpret_cast<const float4*>(src + 4);
    short8 sH, sM, sL;
    const float v[8] = {a.x, a.y, a.z, a.w, b.x, b.y, b.z, b.w};
#pragma unroll
    for (int j = 0; j < 8; ++j) {
        short h, m, l; split3(v[j], h, m, l);
        sH[j] = h; sM[j] = m; sL[j] = l;
    }
    char* base = dst + (size_t)tile * WSB + e * 128 + ((q ^ (e & 7)) << 4);
    *reinterpret_cast<short8*>(base)            = sH;
    *reinterpret_cast<short8*>(base + WCMP)     = sM;
    *reinterpret_cast<short8*>(base + 2 * WCMP) = sL;
}

__global__ __launch_bounds__(512, 2) void router_kernel(
    const float* __restrict__ x, const char* __restrict__ wsAll,
    float* __restrict__ out, float* __restrict__ expert_sums,
    unsigned int* __restrict__ done_ctr)
{
    __shared__ __align__(16) char smem[81920];

    const int tid  = threadIdx.x;
    const int lane = tid & 63;
    const int w    = tid >> 6;           // wave id 0..7
    const int mt   = w & 3;              // M-tile (16 tokens each)
    const int kh   = w >> 2;             // K-half of each BK64 tile
    const int tok0 = blockIdx.x * BM;

    f32x4 acc[4];
#pragma unroll
    for (int nt = 0; nt < 4; ++nt) acc[nt] = (f32x4){0.f, 0.f, 0.f, 0.f};

    // ---- x staging: wave w stages rows [w*8, w*8+8); 2 instrs ----
    auto stageX = [&](int buf, int tile) {
#pragma unroll
        for (int i = 0; i < 2; ++i) {
            const int r0 = w * 8 + i * 4;
            const int r  = r0 + (lane >> 4);
            const int c  = lane & 15;
            const float* src = x + (size_t)(tok0 + r) * DMODEL + tile * BK
                                 + ((c ^ (r & 15)) << 2);
            gload16(src, smem + XS + buf * XSB + r0 * 256 + (lane << 4));
        }
    };
    // ---- W staging: pre-split bf16x3, linear copy; 3 instrs ----
    auto stageW = [&](int buf, int tile) {
        const char* src = wsAll + (size_t)tile * WSB + w * 1024 + (lane << 4);
        char* dst = smem + WS + buf * WSB + w * 1024 + (lane << 4);
#pragma unroll
        for (int j = 0; j < 3; ++j)
            gload16(src + j * WCMP, dst + j * WCMP);
    };

    // prologue: tile 0 (5 loads in flight)
    stageX(0, 0);
    stageW(0, 0);

    int buf = 0;
    for (int tile = 0; tile < NTILE; ++tile) {
        if (tile + 1 < NTILE) {
            stageX(buf ^ 1, tile + 1);
            stageW(buf ^ 1, tile + 1);
            asm volatile("s_waitcnt vmcnt(5)" ::: "memory");  // tile's 5 landed
        } else {
            asm volatile("s_waitcnt vmcnt(0)" ::: "memory");
        }
        __builtin_amdgcn_sched_barrier(0);
        __builtin_amdgcn_s_barrier();            // (a) buf ready block-wide

        // this wave's K32 half: ks = kh
        {
            const int ks = kh;
            const int rl = mt * 16 + (lane & 15);
            const int c0 = ks * 8 + (lane >> 4) * 2;
            const char* xrow = smem + XS + buf * XSB + rl * 256;
            const float4 xa = *reinterpret_cast<const float4*>(
                xrow + ((c0 ^ (lane & 15)) << 4));
            const float4 xb = *reinterpret_cast<const float4*>(
                xrow + (((c0 + 1) ^ (lane & 15)) << 4));
            short8 aH, aM, aL;
            {
                float v[8] = {xa.x, xa.y, xa.z, xa.w, xb.x, xb.y, xb.z, xb.w};
#pragma unroll
                for (int j = 0; j < 8; ++j) {
                    short h, m, l; split3(v[j], h, m, l);
                    aH[j] = h; aM[j] = m; aL[j] = l;
                }
            }
#pragma unroll
            for (int nt = 0; nt < 4; ++nt) {
                const int ef = nt * 16 + (lane & 15);
                const int q  = ks * 4 + (lane >> 4);
                const char* wrow = smem + WS + buf * WSB + ef * 128
                                 + ((q ^ (ef & 7)) << 4);
                const short8 bH = *reinterpret_cast<const short8*>(wrow);
                const short8 bM = *reinterpret_cast<const short8*>(wrow + WCMP);
                const short8 bL = *reinterpret_cast<const short8*>(wrow + 2 * WCMP);
                acc[nt] = __builtin_amdgcn_mfma_f32_16x16x32_bf16(aH, bH, acc[nt], 0, 0, 0);
                acc[nt] = __builtin_amdgcn_mfma_f32_16x16x32_bf16(aH, bM, acc[nt], 0, 0, 0);
                acc[nt] = __builtin_amdgcn_mfma_f32_16x16x32_bf16(aM, bH, acc[nt], 0, 0, 0);
                acc[nt] = __builtin_amdgcn_mfma_f32_16x16x32_bf16(aH, bL, acc[nt], 0, 0, 0);
                acc[nt] = __builtin_amdgcn_mfma_f32_16x16x32_bf16(aM, bM, acc[nt], 0, 0, 0);
                acc[nt] = __builtin_amdgcn_mfma_f32_16x16x32_bf16(aL, bH, acc[nt], 0, 0, 0);
            }
        }
        __builtin_amdgcn_s_barrier();            // (b) all done reading buf
        buf ^= 1;
    }

    // ---- combine K-halves into LDS logits [64 tok][68 f32 stride] ----
    // C/D layout: col=lane&15 (expert frag), row=(lane>>4)*4+r (verified R10)
    if (kh == 0) {
#pragma unroll
        for (int nt = 0; nt < 4; ++nt)
#pragma unroll
            for (int r = 0; r < 4; ++r) {
                const int t = mt * 16 + (lane >> 4) * 4 + r;
                const int e = nt * 16 + (lane & 15);
                *reinterpret_cast<float*>(smem + t * LSTR + e * 4) = acc[nt][r];
            }
    }
    __syncthreads();
    if (kh == 1) {
#pragma unroll
        for (int nt = 0; nt < 4; ++nt)
#pragma unroll
            for (int r = 0; r < 4; ++r) {
                const int t = mt * 16 + (lane >> 4) * 4 + r;
                const int e = nt * 16 + (lane & 15);
                float* p = reinterpret_cast<float*>(smem + t * LSTR + e * 4);
                *p += acc[nt][r];
            }
    }
    __syncthreads();

    float* maxArr = reinterpret_cast<float*>(smem + 18432);
    float* invArr = reinterpret_cast<float*>(smem + 18688);
    float* psum   = reinterpret_cast<float*>(smem + 18944);
    int*   isLast = reinterpret_cast<int*>(smem + 20992);

    // pass 1: per-token max, softmax denom, top-2, outputs (threads 0..63)
    if (tid < BM) {
        const char* lrow = smem + tid * LSTR;
        float4 L[16];
#pragma unroll
        for (int i = 0; i < 16; ++i)
            L[i] = *reinterpret_cast<const float4*>(lrow + i * 16);

        float mx = -INFINITY;
#pragma unroll
        for (int i = 0; i < 16; ++i)
            mx = fmaxf(mx, fmaxf(fmaxf(L[i].x, L[i].y), fmaxf(L[i].z, L[i].w)));

        float v0 = -INFINITY, v1 = -INFINITY;
        int   i0 = NEXP, i1 = NEXP;
        float s = 0.f;
#pragma unroll
        for (int i = 0; i < 16; ++i) {
            const float vv[4] = {L[i].x, L[i].y, L[i].z, L[i].w};
#pragma unroll
            for (int c = 0; c < 4; ++c) {
                const float v = vv[c];
                const int  gi = i * 4 + c;
                s += __expf(v - mx);
                if (v > v0) { v1 = v0; i1 = i0; v0 = v; i0 = gi; }
                else if (v > v1) { v1 = v; i1 = gi; }
            }
        }
        maxArr[tid] = mx;
        invArr[tid] = 1.0f / s;

        const float q = __expf(v1 - v0);
        const float d = 1.0f + q;
        const size_t tok = (size_t)tok0 + tid;
        reinterpret_cast<float2*>(out)[tok]            = make_float2((float)i0, (float)i1);
        reinterpret_cast<float2*>(out + 2 * NTOK)[tok] = make_float2(1.0f / d, q / d);
    }
    __syncthreads();

    // pass 2: per-expert prob sums (512 threads: e = tid&63, grp = tid>>6)
    {
        const int e = tid & 63, grp = tid >> 6;
        float s = 0.f;
#pragma unroll
        for (int i = 0; i < 8; ++i) {
            const int t = grp * 8 + i;
            const float lg = *reinterpret_cast<const float*>(smem + t * LSTR + e * 4);
            s += __expf(lg - maxArr[t]) * invArr[t];
        }
        psum[grp * 64 + e] = s;
    }
    __syncthreads();
    if (tid < 64) {
        float s = 0.f;
#pragma unroll
        for (int g = 0; g < 8; ++g) s += psum[g * 64 + tid];
        atomicAdd(&expert_sums[tid], s);
    }

    // ---- inline loss: last block to finish computes it ----
    if (tid == 0) {
        __threadfence();                         // release our sums add
        unsigned t = atomicAdd(done_ctr, 1u);
        *isLast = (t == (unsigned)(gridDim.x - 1));
    }
    __syncthreads();
    if (*isLast && tid < 64) {
        __threadfence();                         // acquire all blocks' adds
        // read through L2 via atomic RMW (L1 may be stale per G16)
        float pv = atomicAdd(&expert_sums[tid], 0.0f) * (1.0f / (float)NTOK);
        float m = pv;
#pragma unroll
        for (int off = 32; off; off >>= 1) m += __shfl_xor(m, off, 64);
        m *= (1.0f / (float)NEXP);
        float dd = pv - m;
        float vv = dd * dd;
#pragma unroll
        for (int off = 32; off; off >>= 1) vv += __shfl_xor(vv, off, 64);
        vv *= (1.0f / (float)(NEXP - 1));        // ddof=1
        if (tid == 0) {
            float stdv = sqrtf(vv);
            float r = stdv / (m + 1e-6f);
            out[4 * NTOK] = r * r;
        }
    }
}

// ========== fallback (ws too small): R11 kernel + separate loss ==========
__global__ __launch_bounds__(512, 2) void router_fallback(
    const float* __restrict__ x, const float* __restrict__ W,
    float* __restrict__ out, float* __restrict__ expert_sums)
{
    __shared__ __align__(16) char smem[81920];

    const int tid  = threadIdx.x;
    const int lane = tid & 63;
    const int w    = tid >> 6;
    const int mt   = w & 3;
    const int kh   = w >> 2;
    const int tok0 = blockIdx.x * BM;

    f32x4 acc[4];
#pragma unroll
    for (int nt = 0; nt < 4; ++nt) acc[nt] = (f32x4){0.f, 0.f, 0.f, 0.f};

    auto stageX = [&](int buf, int tile) {
#pragma unroll
        for (int i = 0; i < 2; ++i) {
            const int r0 = w * 8 + i * 4;
            const int r  = r0 + (lane >> 4);
            const int c  = lane & 15;
            const float* src = x + (size_t)(tok0 + r) * DMODEL + tile * BK
                                 + ((c ^ (r & 15)) << 2);
            gload16(src, smem + XS + buf * XSB + r0 * 256 + (lane << 4));
        }
    };

    const int we  = tid >> 3;
    const int wc  = tid & 7;
    const int wph = wc ^ (we & 7);
    const float* wgp = W + (size_t)we * DMODEL + wc * 8;

    auto convW = [&](int buf, float4 a, float4 b) {
        short8 sH, sM, sL;
        float v[8] = {a.x, a.y, a.z, a.w, b.x, b.y, b.z, b.w};
#pragma unroll
        for (int j = 0; j < 8; ++j) {
            short h, m, l; split3(v[j], h, m, l);
            sH[j] = h; sM[j] = m; sL[j] = l;
        }
        char* d = smem + WS + buf * WSB + we * 128 + wph * 16;
        *reinterpret_cast<short8*>(d)             = sH;
        *reinterpret_cast<short8*>(d + WCMP)      = sM;
        *reinterpret_cast<short8*>(d + 2 * WCMP)  = sL;
    };

    stageX(0, 0);
    {
        float4 a = *reinterpret_cast<const float4*>(wgp);
        float4 b = *reinterpret_cast<const float4*>(wgp + 4);
        convW(0, a, b);
    }
    __syncthreads();

    int buf = 0;
    for (int tile = 0; tile < NTILE; ++tile) {
        float4 wa, wb;
        if (tile + 1 < NTILE) {
            stageX(buf ^ 1, tile + 1);
            wa = *reinterpret_cast<const float4*>(wgp + (tile + 1) * BK);
            wb = *reinterpret_cast<const float4*>(wgp + (tile + 1) * BK + 4);
        }
        {
            const int ksl = kh;
            const int rl = mt * 16 + (lane & 15);
            const int c0 = ksl * 8 + (lane >> 4) * 2;
            const char* xrow = smem + XS + buf * XSB + rl * 256;
            const float4 xa = *reinterpret_cast<const float4*>(
                xrow + ((c0 ^ (rl & 15)) << 4));
            const float4 xc = *reinterpret_cast<const float4*>(
                xrow + (((c0 + 1) ^ (rl & 15)) << 4));
            short8 aH, aM, aL;
            {
                float v[8] = {xa.x, xa.y, xa.z, xa.w, xc.x, xc.y, xc.z, xc.w};
#pragma unroll
                for (int j = 0; j < 8; ++j) {
                    short h, m, l; split3(v[j], h, m, l);
                    aH[j] = h; aM[j] = m; aL[j] = l;
                }
            }
#pragma unroll
            for (int nt = 0; nt < 4; ++nt) {
                const int ef = nt * 16 + (lane & 15);
                const int q  = ksl * 4 + (lane >> 4);
                const char* wrow = smem + WS + buf * WSB + ef * 128
                                 + ((q ^ (ef & 7)) << 4);
                const short8 bH = *reinterpret_cast<const short8*>(wrow);
                const short8 bM = *reinterpret_cast<const short8*>(wrow + WCMP);
                const short8 bL = *reinterpret_cast<const short8*>(wrow + 2 * WCMP);
                acc[nt] = __builtin_amdgcn_mfma_f32_16x16x32_bf16(aH, bH, acc[nt], 0, 0, 0);
                acc[nt] = __builtin_amdgcn_mfma_f32_16x16x32_bf16(aH, bM, acc[nt], 0, 0, 0);
                acc[nt] = __builtin_amdgcn_mfma_f32_16x16x32_bf16(aM, bH, acc[nt], 0, 0, 0);
                acc[nt] = __builtin_amdgcn_mfma_f32_16x16x32_bf16(aH, bL, acc[nt], 0, 0, 0);
                acc[nt] = __builtin_amdgcn_mfma_f32_16x16x32_bf16(aM, bM, acc[nt], 0, 0, 0);
                acc[nt] = __builtin_amdgcn_mfma_f32_16x16x32_bf16(aL, bH, acc[nt], 0, 0, 0);
            }
        }
        if (tile + 1 < NTILE) convW(buf ^ 1, wa, wb);
        __syncthreads();
        buf ^= 1;
    }

    if (kh == 0) {
#pragma unroll
        for (int nt = 0; nt < 4; ++nt)
#pragma unroll
            for (int r = 0; r < 4; ++r) {
                const int t = mt * 16 + (lane >> 4) * 4 + r;
                const int e = nt * 16 + (lane & 15);
                *reinterpret_cast<float*>(smem + t * LSTR + e * 4) = acc[nt][r];
            }
    }
    __syncthreads();
    if (kh == 1) {
#pragma unroll
        for (int nt = 0; nt < 4; ++nt)
#pragma unroll
            for (int r = 0; r < 4; ++r) {
                const int t = mt * 16 + (lane >> 4) * 4 + r;
                const int e = nt * 16 + (lane & 15);
                float* p = reinterpret_cast<float*>(smem + t * LSTR + e * 4);
                *p += acc[nt][r];
            }
    }
    __syncthreads();

    float* maxArr = reinterpret_cast<float*>(smem + 18432);
    float* invArr = reinterpret_cast<float*>(smem + 18688);
    float* psum   = reinterpret_cast<float*>(smem + 18944);

    if (tid < BM) {
        const char* lrow = smem + tid * LSTR;
        float4 L[16];
#pragma unroll
        for (int i = 0; i < 16; ++i)
            L[i] = *reinterpret_cast<const float4*>(lrow + i * 16);
        float mx = -INFINITY;
#pragma unroll
        for (int i = 0; i < 16; ++i)
            mx = fmaxf(mx, fmaxf(fmaxf(L[i].x, L[i].y), fmaxf(L[i].z, L[i].w)));
        float v0 = -INFINITY, v1 = -INFINITY;
        int   i0 = NEXP, i1 = NEXP;
        float s = 0.f;
#pragma unroll
        for (int i = 0; i < 16; ++i) {
            const float vv[4] = {L[i].x, L[i].y, L[i].z, L[i].w};
#pragma unroll
            for (int c = 0; c < 4; ++c) {
                const float v = vv[c];
                const int  gi = i * 4 + c;
                s += __expf(v - mx);
                if (v > v0) { v1 = v0; i1 = i0; v0 = v; i0 = gi; }
                else if (v > v1) { v1 = v; i1 = gi; }
            }
        }
        maxArr[tid] = mx;
        invArr[tid] = 1.0f / s;
        const float q = __expf(v1 - v0);
        const float d = 1.0f + q;
        const size_t tok = (size_t)tok0 + tid;
        reinterpret_cast<float2*>(out)[tok]            = make_float2((float)i0, (float)i1);
        reinterpret_cast<float2*>(out + 2 * NTOK)[tok] = make_float2(1.0f / d, q / d);
    }
    __syncthreads();
    {
        const int e = tid & 63, grp = tid >> 6;
        float s = 0.f;
#pragma unroll
        for (int i = 0; i < 8; ++i) {
            const int t = grp * 8 + i;
            const float lg = *reinterpret_cast<const float*>(smem + t * LSTR + e * 4);
            s += __expf(lg - maxArr[t]) * invArr[t];
        }
        psum[grp * 64 + e] = s;
    }
    __syncthreads();
    if (tid < 64) {
        float s = 0.f;
#pragma unroll
        for (int g = 0; g < 8; ++g) s += psum[g * 64 + tid];
        atomicAdd(&expert_sums[tid], s);
    }
}

__global__ void loss_kernel(const float* __restrict__ sums, float* __restrict__ out)
{
    const int lane = threadIdx.x;  // 64 threads
    float pv = sums[lane] * (1.0f / (float)NTOK);
    float m = pv;
#pragma unroll
    for (int off = 32; off; off >>= 1) m += __shfl_xor(m, off, 64);
    m *= (1.0f / (float)NEXP);
    float d = pv - m;
    float v = d * d;
#pragma unroll
    for (int off = 32; off; off >>= 1) v += __shfl_xor(v, off, 64);
    v *= (1.0f / (float)(NEXP - 1));  // ddof=1
    if (lane == 0) {
        float stdv = sqrtf(v);
        float r = stdv / (m + 1e-6f);
        out[4 * NTOK] = r * r;
    }
}

extern "C" void kernel_launch(void* const* d_in, const int* in_sizes, int n_in,
                              void* d_out, int out_size, void* d_ws, size_t ws_size,
                              hipStream_t stream)
{
    const float* x = (const float*)d_in[0];
    const float* W = (const float*)d_in[1];
    float* out  = (float*)d_out;
    float* sums = (float*)d_ws;

    if (ws_size >= WSPLIT_OFF + WSPLIT_BYTES) {
        char* wsAll = (char*)d_ws + WSPLIT_OFF;
        unsigned int* ctr = (unsigned int*)((char*)d_ws + 256);
        hipLaunchKernelGGL(prep_kernel, dim3(32), dim3(256), 0, stream,
                           W, wsAll, (int*)d_ws);
        hipLaunchKernelGGL(router_kernel, dim3(NTOK / BM), dim3(512), 0, stream,
                           x, wsAll, out, sums, ctr);
    } else {
        hipMemsetAsync(d_ws, 0, 256, stream);
        hipLaunchKernelGGL(router_fallback, dim3(NTOK / BM), dim3(512), 0, stream,
                           x, W, out, sums);
        hipLaunchKernelGGL(loss_kernel, dim3(1), dim3(64), 0, stream, sums, out);
    }
}

// Round 18
// 52.663 us; speedup vs baseline: 1.2337x; 1.0120x over previous
//
#include <hip/hip_runtime.h>
#include <math.h>
#include <stdint.h>

// Router: x (4,8192,1024) f32, W (64,1024) f32
// out = [ top_idx (32768,2) as float | top_gates (32768,2) | loss (1) ]
// ws  = [0,256): expert prob sums | [256, 256+384K): pre-split W bf16x3
//
// FINAL (R18 = R12 verbatim, measured session-best 51.6us):
//  - MFMA with exact 3-way bf16 split (fp32 = hi+mid+lo, 6 passes), error
//    <= 2^-23 rel — absmax identical to fp32-FMA versions (0.0039).
//  - W pre-split ONCE into global (wsplit_kernel); k-loop staging is pure
//    global_load_lds (5/thread/tile): 2 x-loads + 3 W-loads.
//  - counted-vmcnt double barrier per tile: stage(t+1); vmcnt(5); barrier;
//    MFMA; barrier — staging loads stay in flight across barriers.
//  - BM=64, 512 thr (8 waves = 4 M-tiles x 2 K-halves), LDS 80KB, 2 blk/CU.
// Session record (R10-R17): eight schedule structures all land 51-65us;
// limiter is distributed memory latency (no pipe >15% busy; FETCH = one
// read of x+W; conflicts 0). 6-pass split is precision-locked (4-pass
// risks top-2 index flips at the 1.26 absmax threshold).

constexpr int DMODEL = 1024;
constexpr int NEXP   = 64;
constexpr int BM     = 64;    // tokens per block
constexpr int BK     = 64;    // K per tile
constexpr int NTOK   = 32768;
constexpr int NTILE  = DMODEL / BK;  // 16

// LDS map (bytes), total 81920 (80 KB), 2 blocks/CU:
//   XS @ 0     : fp32 x tile [2][64][64], chunk-swizzled        (32768)
//   WS @ 32768 : bf16 W split [2][3 comp][64 e][64 k], swizzled (49152)
// epilogue overlay @0: logits [64][68 f32], maxArr@18432, invArr@18688,
//   psum[8][64]@18944
constexpr int XS   = 0;
constexpr int XSB  = 64 * 64 * 4;           // 16384 per buffer
constexpr int WS   = 32768;
constexpr int WSB  = 3 * 64 * 64 * 2;       // 24576 per buffer
constexpr int WCMP = 64 * 64 * 2;           // 8192 per component
constexpr int LSTR = 68 * 4;                // logits row stride (bytes)

constexpr size_t WSPLIT_OFF   = 256;
constexpr size_t WSPLIT_BYTES = (size_t)NTILE * WSB;   // 393216

typedef __attribute__((ext_vector_type(8))) short short8;
typedef __attribute__((ext_vector_type(4))) float f32x4;

__device__ __forceinline__ void gload16(const void* g, void* l) {
    __builtin_amdgcn_global_load_lds(
        (const __attribute__((address_space(1))) unsigned int*)g,
        (__attribute__((address_space(3))) unsigned int*)l,
        16, 0, 0);
}

// split one fp32 into 3 bf16 (truncation chunks; x = h+m+l exact to 2^-24)
__device__ __forceinline__ void split3(float x, short& h, short& m, short& l) {
    uint32_t u  = __float_as_uint(x);
    uint32_t uh = u & 0xffff0000u;
    float    r  = x - __uint_as_float(uh);
    uint32_t ur = __float_as_uint(r);
    uint32_t um = ur & 0xffff0000u;
    float    r2 = r - __uint_as_float(um);
    h = (short)(uh >> 16);
    m = (short)(um >> 16);
    l = (short)(__float_as_uint(r2) >> 16);
}

// ---- one-shot W pre-split: 8192 threads, thread g = (expert e, 8-chunk c) ----
__global__ void wsplit_kernel(const float* __restrict__ W, char* __restrict__ dst)
{
    const int g = blockIdx.x * 256 + threadIdx.x;   // 0..8191
    const int e = g >> 7;        // expert 0..63
    const int c = g & 127;       // 8-float chunk within the 1024-k row
    const int tile = c >> 3;
    const int q    = c & 7;
    const float* src = W + (size_t)e * DMODEL + c * 8;
    const float4 a = *reinterpret_cast<const float4*>(src);
    const float4 b = *reinterpret_cast<const float4*>(src + 4);
    short8 sH, sM, sL;
    const float v[8] = {a.x, a.y, a.z, a.w, b.x, b.y, b.z, b.w};
#pragma unroll
    for (int j = 0; j < 8; ++j) {
        short h, m, l; split3(v[j], h, m, l);
        sH[j] = h; sM[j] = m; sL[j] = l;
    }
    char* base = dst + (size_t)tile * WSB + e * 128 + ((q ^ (e & 7)) << 4);
    *reinterpret_cast<short8*>(base)            = sH;
    *reinterpret_cast<short8*>(base + WCMP)     = sM;
    *reinterpret_cast<short8*>(base + 2 * WCMP) = sL;
}

__global__ __launch_bounds__(512, 2) void router_kernel(
    const float* __restrict__ x, const char* __restrict__ wsAll,
    float* __restrict__ out, float* __restrict__ expert_sums)
{
    __shared__ __align__(16) char smem[81920];

    const int tid  = threadIdx.x;
    const int lane = tid & 63;
    const int w    = tid >> 6;           // wave id 0..7
    const int mt   = w & 3;              // M-tile (16 tokens each)
    const int kh   = w >> 2;             // K-half of each BK64 tile
    const int tok0 = blockIdx.x * BM;

    f32x4 acc[4];
#pragma unroll
    for (int nt = 0; nt < 4; ++nt) acc[nt] = (f32x4){0.f, 0.f, 0.f, 0.f};

    // ---- x staging: wave w stages rows [w*8, w*8+8); 2 instrs ----
    auto stageX = [&](int buf, int tile) {
#pragma unroll
        for (int i = 0; i < 2; ++i) {
            const int r0 = w * 8 + i * 4;
            const int r  = r0 + (lane >> 4);
            const int c  = lane & 15;
            const float* src = x + (size_t)(tok0 + r) * DMODEL + tile * BK
                                 + ((c ^ (r & 15)) << 2);
            gload16(src, smem + XS + buf * XSB + r0 * 256 + (lane << 4));
        }
    };
    // ---- W staging: pre-split bf16x3, linear copy; 3 instrs ----
    auto stageW = [&](int buf, int tile) {
        const char* src = wsAll + (size_t)tile * WSB + w * 1024 + (lane << 4);
        char* dst = smem + WS + buf * WSB + w * 1024 + (lane << 4);
#pragma unroll
        for (int j = 0; j < 3; ++j)
            gload16(src + j * WCMP, dst + j * WCMP);
    };

    // prologue: tile 0 (5 loads in flight)
    stageX(0, 0);
    stageW(0, 0);

    int buf = 0;
    for (int tile = 0; tile < NTILE; ++tile) {
        if (tile + 1 < NTILE) {
            stageX(buf ^ 1, tile + 1);
            stageW(buf ^ 1, tile + 1);
            asm volatile("s_waitcnt vmcnt(5)" ::: "memory");  // tile's 5 landed
        } else {
            asm volatile("s_waitcnt vmcnt(0)" ::: "memory");
        }
        __builtin_amdgcn_sched_barrier(0);
        __builtin_amdgcn_s_barrier();            // (a) buf ready block-wide

        // this wave's K32 half: ks = kh
        {
            const int ks = kh;
            const int rl = mt * 16 + (lane & 15);
            const int c0 = ks * 8 + (lane >> 4) * 2;
            const char* xrow = smem + XS + buf * XSB + rl * 256;
            const float4 xa = *reinterpret_cast<const float4*>(
                xrow + ((c0 ^ (lane & 15)) << 4));
            const float4 xb = *reinterpret_cast<const float4*>(
                xrow + (((c0 + 1) ^ (lane & 15)) << 4));
            short8 aH, aM, aL;
            {
                float v[8] = {xa.x, xa.y, xa.z, xa.w, xb.x, xb.y, xb.z, xb.w};
#pragma unroll
                for (int j = 0; j < 8; ++j) {
                    short h, m, l; split3(v[j], h, m, l);
                    aH[j] = h; aM[j] = m; aL[j] = l;
                }
            }
#pragma unroll
            for (int nt = 0; nt < 4; ++nt) {
                const int ef = nt * 16 + (lane & 15);
                const int q  = ks * 4 + (lane >> 4);
                const char* wrow = smem + WS + buf * WSB + ef * 128
                                 + ((q ^ (ef & 7)) << 4);
                const short8 bH = *reinterpret_cast<const short8*>(wrow);
                const short8 bM = *reinterpret_cast<const short8*>(wrow + WCMP);
                const short8 bL = *reinterpret_cast<const short8*>(wrow + 2 * WCMP);
                acc[nt] = __builtin_amdgcn_mfma_f32_16x16x32_bf16(aH, bH, acc[nt], 0, 0, 0);
                acc[nt] = __builtin_amdgcn_mfma_f32_16x16x32_bf16(aH, bM, acc[nt], 0, 0, 0);
                acc[nt] = __builtin_amdgcn_mfma_f32_16x16x32_bf16(aM, bH, acc[nt], 0, 0, 0);
                acc[nt] = __builtin_amdgcn_mfma_f32_16x16x32_bf16(aH, bL, acc[nt], 0, 0, 0);
                acc[nt] = __builtin_amdgcn_mfma_f32_16x16x32_bf16(aM, bM, acc[nt], 0, 0, 0);
                acc[nt] = __builtin_amdgcn_mfma_f32_16x16x32_bf16(aL, bH, acc[nt], 0, 0, 0);
            }
        }
        __builtin_amdgcn_s_barrier();            // (b) all done reading buf
        buf ^= 1;
    }

    // ---- combine K-halves into LDS logits [64 tok][68 f32 stride] ----
    // C/D layout: col=lane&15 (expert frag), row=(lane>>4)*4+r (verified R10)
    if (kh == 0) {
#pragma unroll
        for (int nt = 0; nt < 4; ++nt)
#pragma unroll
            for (int r = 0; r < 4; ++r) {
                const int t = mt * 16 + (lane >> 4) * 4 + r;
                const int e = nt * 16 + (lane & 15);
                *reinterpret_cast<float*>(smem + t * LSTR + e * 4) = acc[nt][r];
            }
    }
    __syncthreads();
    if (kh == 1) {
#pragma unroll
        for (int nt = 0; nt < 4; ++nt)
#pragma unroll
            for (int r = 0; r < 4; ++r) {
                const int t = mt * 16 + (lane >> 4) * 4 + r;
                const int e = nt * 16 + (lane & 15);
                float* p = reinterpret_cast<float*>(smem + t * LSTR + e * 4);
                *p += acc[nt][r];
            }
    }
    __syncthreads();

    float* maxArr = reinterpret_cast<float*>(smem + 18432);
    float* invArr = reinterpret_cast<float*>(smem + 18688);
    float* psum   = reinterpret_cast<float*>(smem + 18944);

    // pass 1: per-token max, softmax denom, top-2, outputs (threads 0..63)
    if (tid < BM) {
        const char* lrow = smem + tid * LSTR;
        float4 L[16];
#pragma unroll
        for (int i = 0; i < 16; ++i)
            L[i] = *reinterpret_cast<const float4*>(lrow + i * 16);

        float mx = -INFINITY;
#pragma unroll
        for (int i = 0; i < 16; ++i)
            mx = fmaxf(mx, fmaxf(fmaxf(L[i].x, L[i].y), fmaxf(L[i].z, L[i].w)));

        float v0 = -INFINITY, v1 = -INFINITY;
        int   i0 = NEXP, i1 = NEXP;
        float s = 0.f;
#pragma unroll
        for (int i = 0; i < 16; ++i) {
            const float vv[4] = {L[i].x, L[i].y, L[i].z, L[i].w};
#pragma unroll
            for (int c = 0; c < 4; ++c) {
                const float v = vv[c];
                const int  gi = i * 4 + c;
                s += __expf(v - mx);
                if (v > v0) { v1 = v0; i1 = i0; v0 = v; i0 = gi; }
                else if (v > v1) { v1 = v; i1 = gi; }
            }
        }
        maxArr[tid] = mx;
        invArr[tid] = 1.0f / s;

        const float q = __expf(v1 - v0);
        const float d = 1.0f + q;
        const size_t tok = (size_t)tok0 + tid;
        reinterpret_cast<float2*>(out)[tok]            = make_float2((float)i0, (float)i1);
        reinterpret_cast<float2*>(out + 2 * NTOK)[tok] = make_float2(1.0f / d, q / d);
    }
    __syncthreads();

    // pass 2: per-expert prob sums (512 threads: e = tid&63, grp = tid>>6)
    {
        const int e = tid & 63, grp = tid >> 6;
        float s = 0.f;
#pragma unroll
        for (int i = 0; i < 8; ++i) {
            const int t = grp * 8 + i;
            const float lg = *reinterpret_cast<const float*>(smem + t * LSTR + e * 4);
            s += __expf(lg - maxArr[t]) * invArr[t];
        }
        psum[grp * 64 + e] = s;
    }
    __syncthreads();
    if (tid < 64) {
        float s = 0.f;
#pragma unroll
        for (int g = 0; g < 8; ++g) s += psum[g * 64 + tid];
        atomicAdd(&expert_sums[tid], s);
    }
}

// ================= fallback: LDS-convW kernel (ws too small) =============
__global__ __launch_bounds__(512, 2) void router_fallback(
    const float* __restrict__ x, const float* __restrict__ W,
    float* __restrict__ out, float* __restrict__ expert_sums)
{
    __shared__ __align__(16) char smem[81920];

    const int tid  = threadIdx.x;
    const int lane = tid & 63;
    const int w    = tid >> 6;
    const int mt   = w & 3;
    const int kh   = w >> 2;
    const int tok0 = blockIdx.x * BM;

    f32x4 acc[4];
#pragma unroll
    for (int nt = 0; nt < 4; ++nt) acc[nt] = (f32x4){0.f, 0.f, 0.f, 0.f};

    auto stageX = [&](int buf, int tile) {
#pragma unroll
        for (int i = 0; i < 2; ++i) {
            const int r0 = w * 8 + i * 4;
            const int r  = r0 + (lane >> 4);
            const int c  = lane & 15;
            const float* src = x + (size_t)(tok0 + r) * DMODEL + tile * BK
                                 + ((c ^ (r & 15)) << 2);
            gload16(src, smem + XS + buf * XSB + r0 * 256 + (lane << 4));
        }
    };

    const int we  = tid >> 3;
    const int wc  = tid & 7;
    const int wph = wc ^ (we & 7);
    const float* wgp = W + (size_t)we * DMODEL + wc * 8;

    auto convW = [&](int buf, float4 a, float4 b) {
        short8 sH, sM, sL;
        float v[8] = {a.x, a.y, a.z, a.w, b.x, b.y, b.z, b.w};
#pragma unroll
        for (int j = 0; j < 8; ++j) {
            short h, m, l; split3(v[j], h, m, l);
            sH[j] = h; sM[j] = m; sL[j] = l;
        }
        char* d = smem + WS + buf * WSB + we * 128 + wph * 16;
        *reinterpret_cast<short8*>(d)             = sH;
        *reinterpret_cast<short8*>(d + WCMP)      = sM;
        *reinterpret_cast<short8*>(d + 2 * WCMP)  = sL;
    };

    stageX(0, 0);
    {
        float4 a = *reinterpret_cast<const float4*>(wgp);
        float4 b = *reinterpret_cast<const float4*>(wgp + 4);
        convW(0, a, b);
    }
    __syncthreads();

    int buf = 0;
    for (int tile = 0; tile < NTILE; ++tile) {
        float4 wa, wb;
        if (tile + 1 < NTILE) {
            stageX(buf ^ 1, tile + 1);
            wa = *reinterpret_cast<const float4*>(wgp + (tile + 1) * BK);
            wb = *reinterpret_cast<const float4*>(wgp + (tile + 1) * BK + 4);
        }
        {
            const int ksl = kh;
            const int rl = mt * 16 + (lane & 15);
            const int c0 = ksl * 8 + (lane >> 4) * 2;
            const char* xrow = smem + XS + buf * XSB + rl * 256;
            const float4 xa = *reinterpret_cast<const float4*>(
                xrow + ((c0 ^ (rl & 15)) << 4));
            const float4 xc = *reinterpret_cast<const float4*>(
                xrow + (((c0 + 1) ^ (rl & 15)) << 4));
            short8 aH, aM, aL;
            {
                float v[8] = {xa.x, xa.y, xa.z, xa.w, xc.x, xc.y, xc.z, xc.w};
#pragma unroll
                for (int j = 0; j < 8; ++j) {
                    short h, m, l; split3(v[j], h, m, l);
                    aH[j] = h; aM[j] = m; aL[j] = l;
                }
            }
#pragma unroll
            for (int nt = 0; nt < 4; ++nt) {
                const int ef = nt * 16 + (lane & 15);
                const int q  = ksl * 4 + (lane >> 4);
                const char* wrow = smem + WS + buf * WSB + ef * 128
                                 + ((q ^ (ef & 7)) << 4);
                const short8 bH = *reinterpret_cast<const short8*>(wrow);
                const short8 bM = *reinterpret_cast<const short8*>(wrow + WCMP);
                const short8 bL = *reinterpret_cast<const short8*>(wrow + 2 * WCMP);
                acc[nt] = __builtin_amdgcn_mfma_f32_16x16x32_bf16(aH, bH, acc[nt], 0, 0, 0);
                acc[nt] = __builtin_amdgcn_mfma_f32_16x16x32_bf16(aH, bM, acc[nt], 0, 0, 0);
                acc[nt] = __builtin_amdgcn_mfma_f32_16x16x32_bf16(aM, bH, acc[nt], 0, 0, 0);
                acc[nt] = __builtin_amdgcn_mfma_f32_16x16x32_bf16(aH, bL, acc[nt], 0, 0, 0);
                acc[nt] = __builtin_amdgcn_mfma_f32_16x16x32_bf16(aM, bM, acc[nt], 0, 0, 0);
                acc[nt] = __builtin_amdgcn_mfma_f32_16x16x32_bf16(aL, bH, acc[nt], 0, 0, 0);
            }
        }
        if (tile + 1 < NTILE) convW(buf ^ 1, wa, wb);
        __syncthreads();
        buf ^= 1;
    }

    if (kh == 0) {
#pragma unroll
        for (int nt = 0; nt < 4; ++nt)
#pragma unroll
            for (int r = 0; r < 4; ++r) {
                const int t = mt * 16 + (lane >> 4) * 4 + r;
                const int e = nt * 16 + (lane & 15);
                *reinterpret_cast<float*>(smem + t * LSTR + e * 4) = acc[nt][r];
            }
    }
    __syncthreads();
    if (kh == 1) {
#pragma unroll
        for (int nt = 0; nt < 4; ++nt)
#pragma unroll
            for (int r = 0; r < 4; ++r) {
                const int t = mt * 16 + (lane >> 4) * 4 + r;
                const int e = nt * 16 + (lane & 15);
                float* p = reinterpret_cast<float*>(smem + t * LSTR + e * 4);
                *p += acc[nt][r];
            }
    }
    __syncthreads();

    float* maxArr = reinterpret_cast<float*>(smem + 18432);
    float* invArr = reinterpret_cast<float*>(smem + 18688);
    float* psum   = reinterpret_cast<float*>(smem + 18944);

    if (tid < BM) {
        const char* lrow = smem + tid * LSTR;
        float4 L[16];
#pragma unroll
        for (int i = 0; i < 16; ++i)
            L[i] = *reinterpret_cast<const float4*>(lrow + i * 16);
        float mx = -INFINITY;
#pragma unroll
        for (int i = 0; i < 16; ++i)
            mx = fmaxf(mx, fmaxf(fmaxf(L[i].x, L[i].y), fmaxf(L[i].z, L[i].w)));
        float v0 = -INFINITY, v1 = -INFINITY;
        int   i0 = NEXP, i1 = NEXP;
        float s = 0.f;
#pragma unroll
        for (int i = 0; i < 16; ++i) {
            const float vv[4] = {L[i].x, L[i].y, L[i].z, L[i].w};
#pragma unroll
            for (int c = 0; c < 4; ++c) {
                const float v = vv[c];
                const int  gi = i * 4 + c;
                s += __expf(v - mx);
                if (v > v0) { v1 = v0; i1 = i0; v0 = v; i0 = gi; }
                else if (v > v1) { v1 = v; i1 = gi; }
            }
        }
        maxArr[tid] = mx;
        invArr[tid] = 1.0f / s;
        const float q = __expf(v1 - v0);
        const float d = 1.0f + q;
        const size_t tok = (size_t)tok0 + tid;
        reinterpret_cast<float2*>(out)[tok]            = make_float2((float)i0, (float)i1);
        reinterpret_cast<float2*>(out + 2 * NTOK)[tok] = make_float2(1.0f / d, q / d);
    }
    __syncthreads();
    {
        const int e = tid & 63, grp = tid >> 6;
        float s = 0.f;
#pragma unroll
        for (int i = 0; i < 8; ++i) {
            const int t = grp * 8 + i;
            const float lg = *reinterpret_cast<const float*>(smem + t * LSTR + e * 4);
            s += __expf(lg - maxArr[t]) * invArr[t];
        }
        psum[grp * 64 + e] = s;
    }
    __syncthreads();
    if (tid < 64) {
        float s = 0.f;
#pragma unroll
        for (int g = 0; g < 8; ++g) s += psum[g * 64 + tid];
        atomicAdd(&expert_sums[tid], s);
    }
}

__global__ void loss_kernel(const float* __restrict__ sums, float* __restrict__ out)
{
    const int lane = threadIdx.x;  // 64 threads
    float pv = sums[lane] * (1.0f / (float)NTOK);  // avg_probs[lane]
    float m = pv;
#pragma unroll
    for (int off = 32; off; off >>= 1) m += __shfl_xor(m, off, 64);
    m *= (1.0f / (float)NEXP);
    float d = pv - m;
    float v = d * d;
#pragma unroll
    for (int off = 32; off; off >>= 1) v += __shfl_xor(v, off, 64);
    v *= (1.0f / (float)(NEXP - 1));  // ddof=1
    if (lane == 0) {
        float stdv = sqrtf(v);
        float r = stdv / (m + 1e-6f);
        out[4 * NTOK] = r * r;
    }
}

extern "C" void kernel_launch(void* const* d_in, const int* in_sizes, int n_in,
                              void* d_out, int out_size, void* d_ws, size_t ws_size,
                              hipStream_t stream)
{
    const float* x = (const float*)d_in[0];
    const float* W = (const float*)d_in[1];
    float* out  = (float*)d_out;
    float* sums = (float*)d_ws;

    hipMemsetAsync(d_ws, 0, 256, stream);

    if (ws_size >= WSPLIT_OFF + WSPLIT_BYTES) {
        char* wsAll = (char*)d_ws + WSPLIT_OFF;
        hipLaunchKernelGGL(wsplit_kernel, dim3(32), dim3(256), 0, stream, W, wsAll);
        hipLaunchKernelGGL(router_kernel, dim3(NTOK / BM), dim3(512), 0, stream,
                           x, wsAll, out, sums);
    } else {
        hipLaunchKernelGGL(router_fallback, dim3(NTOK / BM), dim3(512), 0, stream,
                           x, W, out, sums);
    }
    hipLaunchKernelGGL(loss_kernel, dim3(1), dim3(64), 0, stream, sums, out);
}